// Round 6
// baseline (70.425 us; speedup 1.0000x reference)
//
#include <hip/hip_runtime.h>
#include <math.h>

#define NV 24
#define NB 8
#define NS 512
#define NTOK 4096       // NB*NS
#define H1 128
#define H2 64
#define SH1 256
#define SH2 128
#define IH 32
#define NP 576          // NV*NV

typedef short bf16x8 __attribute__((ext_vector_type(8)));
typedef float f32x4 __attribute__((ext_vector_type(4)));

__device__ __forceinline__ short f2bf(float f) {
    union { float f; unsigned u; } x; x.f = f;
    unsigned r = x.u + 0x7fffu + ((x.u >> 16) & 1u);   // RNE
    return (short)(r >> 16);
}

// 256-thread block sum-reduce (4 waves)
__device__ __forceinline__ float blk_reduce(float x, float* red, int t) {
#pragma unroll
    for (int o = 32; o > 0; o >>= 1) x += __shfl_xor(x, o);
    if ((t & 63) == 0) red[t >> 6] = x;
    __syncthreads();
    float r = red[0] + red[1] + red[2] + red[3];
    __syncthreads();
    return r;
}

// ---------------- ws layout (floats) ----------------
// [0, 576)        cov
// [1024, 99328)   dataT [NV][NTOK]

// K1: transpose data (NTOK x NV) -> dataT (NV x NTOK)
__global__ __launch_bounds__(256) void k_transp(const float* __restrict__ data,
                                                float* __restrict__ dataT) {
    int idx = blockIdx.x * 256 + threadIdx.x;
    int n = idx / NV, v = idx % NV;
    dataT[v * NTOK + n] = data[idx];
}

// K2: blocks 0..575 = covavg (batch-mean + center + dot), 576..1151 = ind MLPs
__global__ __launch_bounds__(256) void k_covind(
    const float* __restrict__ dataT,
    float* __restrict__ cov,
    const float* __restrict__ iW1, const float* __restrict__ ib1,
    const float* __restrict__ iW2, const float* __restrict__ ib2,
    float* __restrict__ out_ind) {
    __shared__ float red[256];
    const int bx = blockIdx.x;
    const int t = threadIdx.x;

    if (bx < NP) {
        // ---- covavg: pair (i,j), avg over batch then centered dot over s ----
        int i = bx / NV, j = bx % NV;
        const float* ri = dataT + i * NTOK;
        const float* rj = dataT + j * NTOK;
        float ai0 = 0.f, ai1 = 0.f, aj0 = 0.f, aj1 = 0.f;
#pragma unroll
        for (int b = 0; b < NB; ++b) {
            ai0 += ri[b * NS + t];       ai1 += ri[b * NS + t + 256];
            aj0 += rj[b * NS + t];       aj1 += rj[b * NS + t + 256];
        }
        ai0 *= 0.125f; ai1 *= 0.125f; aj0 *= 0.125f; aj1 *= 0.125f;
        float si = blk_reduce(ai0 + ai1, red, t);
        float sj = blk_reduce(aj0 + aj1, red, t);
        float mi = si * (1.f / NS), mj = sj * (1.f / NS);
        float sd = (ai0 - mi) * (aj0 - mj) + (ai1 - mi) * (aj1 - mj);
        sd = blk_reduce(sd, red, t);
        if (t == 0) cov[bx] = sd;
    } else {
        // ---- ind: pairwise 2->32->1 MLP, mean sigmoid over 4096 samples ----
        int p = bx - NP;
        int i = p / NV, j = p % NV;
        float w0[IH], w1[IH], bb[IH], w2[IH];
        const float4* A4 = (const float4*)(iW1 + p * 2 * IH);
        const float4* B4 = (const float4*)(ib1 + p * IH);
        const float4* C4 = (const float4*)(iW2 + p * IH);
#pragma unroll
        for (int q = 0; q < 8; ++q) {
            float4 u = A4[q];
            w0[q * 4 + 0] = u.x; w0[q * 4 + 1] = u.y; w0[q * 4 + 2] = u.z; w0[q * 4 + 3] = u.w;
            float4 v4 = A4[8 + q];
            w1[q * 4 + 0] = v4.x; w1[q * 4 + 1] = v4.y; w1[q * 4 + 2] = v4.z; w1[q * 4 + 3] = v4.w;
            float4 b4 = B4[q];
            bb[q * 4 + 0] = b4.x; bb[q * 4 + 1] = b4.y; bb[q * 4 + 2] = b4.z; bb[q * 4 + 3] = b4.w;
            float4 c4 = C4[q];
            w2[q * 4 + 0] = c4.x; w2[q * 4 + 1] = c4.y; w2[q * 4 + 2] = c4.z; w2[q * 4 + 3] = c4.w;
        }
        float b2v = ib2[p];
        const float* di_p = dataT + i * NTOK;
        const float* dj_p = dataT + j * NTOK;
        float acc = 0.f;
#pragma unroll 2
        for (int k = 0; k < NTOK / 256; ++k) {
            int n = k * 256 + t;
            float di = di_p[n];
            float dj = dj_p[n];
            float s = b2v;
#pragma unroll
            for (int h = 0; h < IH; ++h) {
                float a = fmaf(di, w0[h], fmaf(dj, w1[h], bb[h]));
                a = fmaxf(a, 0.f);
                s = fmaf(a, w2[h], s);
            }
            acc += 1.f / (1.f + expf(-s));
        }
        red[t] = acc;
        __syncthreads();
        for (int st = 128; st > 0; st >>= 1) {
            if (t < st) red[t] += red[t + st];
            __syncthreads();
        }
        if (t == 0) out_ind[p] = red[0] * (1.f / NTOK);
    }
}

// K3: full structure MLP in one block: corr -> 576->256->128->576 -> adj
__global__ __launch_bounds__(256) void k_mlp123(
    const float* __restrict__ cov,
    const float* __restrict__ sW1, const float* __restrict__ sb1,
    const float* __restrict__ sW2, const float* __restrict__ sb2,
    const float* __restrict__ sW3, const float* __restrict__ sb3,
    float* __restrict__ out_adj) {
    __shared__ float corrL[NP];
    __shared__ float stdL[NV];
    __shared__ float h1L[SH1];
    __shared__ float h2L[SH2];
    int t = threadIdx.x;
    if (t < NV) stdL[t] = sqrtf(cov[t * (NV + 1)]);
    __syncthreads();
    for (int o = t; o < NP; o += 256) {
        int i = o / NV, j = o % NV;
        float q = fabsf(cov[o] / (stdL[i] * stdL[j]));
        if (isnan(q)) q = 0.f;
        if (i == j) q = 0.f;
        corrL[o] = q;
    }
    __syncthreads();
    {
        float a = sb1[t];
        for (int k = 0; k < NP; ++k) a = fmaf(corrL[k], sW1[k * SH1 + t], a);
        h1L[t] = fmaxf(a, 0.f);
    }
    __syncthreads();
    if (t < SH2) {
        float a = sb2[t];
        for (int k = 0; k < SH1; ++k) a = fmaf(h1L[k], sW2[k * SH2 + t], a);
        h2L[t] = fmaxf(a, 0.f);
    }
    __syncthreads();
    for (int o = t; o < NP; o += 256) {
        float a = sb3[o];
        for (int k = 0; k < SH2; ++k) a = fmaf(h2L[k], sW3[k * NP + o], a);
        float sg = 1.f / (1.f + expf(-a));
        int i = o / NV, j = o % NV;
        out_adj[o] = (j > i) ? sg : 0.f;
    }
}

// K4: per-variable 23->128->64->1 MLP via bf16 MFMA. 128-token chunks, grid 24x32.
// LDS: Xl 10KB | WH 24KB region = {W1B 8KB + W2B 16KB} aliased with {Hl 16KB}
__global__ __launch_bounds__(256) void k_pred(
    const float* __restrict__ data,
    const float* __restrict__ mW1, const float* __restrict__ mb1,
    const float* __restrict__ mW2, const float* __restrict__ mb2,
    const float* __restrict__ mW3, const float* __restrict__ mb3,
    const float* __restrict__ adj,
    float* __restrict__ out_pred) {
    const int v = blockIdx.x;          // 0..23
    const int chunk = blockIdx.y;      // 0..31, 128 tokens each
    const int t = threadIdx.x;

    bool hp = false;
#pragma unroll
    for (int r = 0; r < NV; ++r) hp = hp || (adj[r * NV + v] > 0.5f);
    if (!hp) {
        if (t < 128) {
            int tok = chunk * 128 + t;
            out_pred[tok * NV + v] = data[tok * NV + v];
        }
        return;
    }

    __shared__ short Xl[128 * 40];     // 10 KB
    __shared__ short WH[12288];        // 24 KB
    short* W1B = WH;                   // 32*128
    short* W2B = WH + 4096;            // 128*64
    short* Hl = WH;                    // aliased: 4 waves * 2048 shorts

    if (t < 128) {
        int tok = chunk * 128 + t;
        const float4* dr4 = (const float4*)(data + tok * NV);
        float d[24];
#pragma unroll
        for (int q = 0; q < 6; ++q) {
            float4 u = dr4[q];
            d[q * 4 + 0] = u.x; d[q * 4 + 1] = u.y; d[q * 4 + 2] = u.z; d[q * 4 + 3] = u.w;
        }
        short xr[32];
#pragma unroll
        for (int j = 0; j < 23; ++j) {
            int src = j + (j >= v ? 1 : 0);
            xr[j] = f2bf(d[src]);
        }
        xr[23] = f2bf(1.0f);
#pragma unroll
        for (int j = 24; j < 32; ++j) xr[j] = 0;
        short* xp = Xl + t * 40;
#pragma unroll
        for (int q = 0; q < 4; ++q)
            *(bf16x8*)(xp + q * 8) = *(bf16x8*)(xr + q * 8);
    }
    for (int idx = t; idx < 32 * 128; idx += 256) {
        int k = idx >> 7, h = idx & 127;
        float val = 0.f;
        if (k < 23) {
            int src = k + (k >= v ? 1 : 0);
            float pm = (adj[src * NV + v] > 0.5f) ? 1.f : 0.f;
            val = mW1[(v * 23 + k) * 128 + h] * pm;
        } else if (k == 23) {
            val = mb1[v * 128 + h];
        }
        int nt = h >> 4, nn = h & 15, kb = (k >> 3) & 3, e = k & 7;
        W1B[((nt * 4 + kb) * 16 + nn) * 8 + e] = f2bf(val);
    }
    for (int idx = t; idx < 128 * 64; idx += 256) {
        int k = idx >> 6, n = idx & 63;
        float val = mW2[(v * 128 + k) * 64 + n];
        int s = k >> 5, kb = (k >> 3) & 3, e = k & 7, nt = n >> 4, nn = n & 15;
        W2B[(((s * 4 + nt) * 4 + kb) * 16 + nn) * 8 + e] = f2bf(val);
    }
    __syncthreads();

    const int lane = t & 63;
    const int wid = t >> 6;
    const int ml = lane & 15;
    const int kb = lane >> 4;
    short* Hw = Hl + wid * 2048;

    bf16x8 w1f[8], w2f[16];
#pragma unroll
    for (int nt = 0; nt < 8; ++nt)
        w1f[nt] = *(bf16x8*)(W1B + (nt * 64 + lane) * 8);
#pragma unroll
    for (int q = 0; q < 16; ++q)
        w2f[q] = *(bf16x8*)(W2B + (q * 64 + lane) * 8);

    float b2r[4], w3r[4];
#pragma unroll
    for (int nt = 0; nt < 4; ++nt) {
        b2r[nt] = mb2[v * 64 + nt * 16 + ml];
        w3r[nt] = mW3[v * 64 + nt * 16 + ml];
    }
    float b3v = mb3[v];

    __syncthreads();   // W1B/W2B fully read before Hl (aliased) is written

#pragma unroll
    for (int mt = 0; mt < 2; ++mt) {
        int lt = wid * 32 + mt * 16 + ml;      // local token row (0..127)
        bf16x8 a1 = *(bf16x8*)(Xl + lt * 40 + kb * 8);
        f32x4 c1[8] = {};
#pragma unroll
        for (int nt = 0; nt < 8; ++nt)
            c1[nt] = __builtin_amdgcn_mfma_f32_16x16x32_bf16(a1, w1f[nt], c1[nt], 0, 0, 0);
#pragma unroll
        for (int nt = 0; nt < 8; ++nt) {
#pragma unroll
            for (int r = 0; r < 4; ++r) {
                int m = kb * 4 + r;
                int h = nt * 16 + ml;
                int bo = (m * 256 + h * 2) ^ ((m & 7) << 4);
                *(short*)((char*)Hw + bo) = f2bf(fmaxf(c1[nt][r], 0.f));
            }
        }
        f32x4 c2[4] = {};
#pragma unroll
        for (int s = 0; s < 4; ++s) {
            int c0 = s * 32 + kb * 8;
            int bo = (ml * 256 + c0 * 2) ^ ((ml & 7) << 4);
            bf16x8 a2 = *(bf16x8*)((char*)Hw + bo);
#pragma unroll
            for (int nt = 0; nt < 4; ++nt)
                c2[nt] = __builtin_amdgcn_mfma_f32_16x16x32_bf16(a2, w2f[s * 4 + nt], c2[nt], 0, 0, 0);
        }
        float sacc[4] = {0.f, 0.f, 0.f, 0.f};
#pragma unroll
        for (int nt = 0; nt < 4; ++nt) {
#pragma unroll
            for (int r = 0; r < 4; ++r)
                sacc[r] += fmaxf(c2[nt][r] + b2r[nt], 0.f) * w3r[nt];
        }
#pragma unroll
        for (int o = 1; o < 16; o <<= 1) {
#pragma unroll
            for (int r = 0; r < 4; ++r)
                sacc[r] += __shfl_xor(sacc[r], o);
        }
        if (ml == 0) {
            int tokb = chunk * 128 + wid * 32 + mt * 16 + kb * 4;
#pragma unroll
            for (int r = 0; r < 4; ++r)
                out_pred[(tokb + r) * NV + v] = sacc[r] + b3v;
        }
    }
}

extern "C" void kernel_launch(void* const* d_in, const int* in_sizes, int n_in,
                              void* d_out, int out_size, void* d_ws, size_t ws_size,
                              hipStream_t stream) {
    const float* data = (const float*)d_in[0];
    const float* sW1 = (const float*)d_in[1];
    const float* sb1 = (const float*)d_in[2];
    const float* sW2 = (const float*)d_in[3];
    const float* sb2 = (const float*)d_in[4];
    const float* sW3 = (const float*)d_in[5];
    const float* sb3 = (const float*)d_in[6];
    const float* mW1 = (const float*)d_in[7];
    const float* mb1 = (const float*)d_in[8];
    const float* mW2 = (const float*)d_in[9];
    const float* mb2 = (const float*)d_in[10];
    const float* mW3 = (const float*)d_in[11];
    const float* mb3 = (const float*)d_in[12];
    const float* iW1 = (const float*)d_in[13];
    const float* ib1 = (const float*)d_in[14];
    const float* iW2 = (const float*)d_in[15];
    const float* ib2 = (const float*)d_in[16];

    float* out = (float*)d_out;
    float* ws = (float*)d_ws;
    float* ws_cov = ws;
    float* ws_dataT = ws + 1024;

    k_transp<<<dim3(384), dim3(256), 0, stream>>>(data, ws_dataT);
    k_covind<<<dim3(1152), dim3(256), 0, stream>>>(ws_dataT, ws_cov,
                                                   iW1, ib1, iW2, ib2,
                                                   out + NP + NTOK * NV);
    k_mlp123<<<dim3(1), dim3(256), 0, stream>>>(ws_cov, sW1, sb1, sW2, sb2,
                                                sW3, sb3, out);
    dim3 gp(NV, 32);
    k_pred<<<gp, dim3(256), 0, stream>>>(data, mW1, mb1, mW2, mb2, mW3, mb3,
                                         out, out + NP);
}

// Round 7
// 67.917 us; speedup vs baseline: 1.0369x; 1.0369x over previous
//
#include <hip/hip_runtime.h>
#include <math.h>

#define NV 24
#define NB 8
#define NS 512
#define NTOK 4096       // NB*NS
#define H1 128
#define H2 64
#define SH1 256
#define SH2 128
#define IH 32
#define NP 576          // NV*NV

typedef short bf16x8 __attribute__((ext_vector_type(8)));
typedef float f32x4 __attribute__((ext_vector_type(4)));

__device__ __forceinline__ short f2bf(float f) {
    union { float f; unsigned u; } x; x.f = f;
    unsigned r = x.u + 0x7fffu + ((x.u >> 16) & 1u);   // RNE
    return (short)(r >> 16);
}

__device__ __forceinline__ float blk_reduce(float x, float* red, int t) {
#pragma unroll
    for (int o = 32; o > 0; o >>= 1) x += __shfl_xor(x, o);
    if ((t & 63) == 0) red[t >> 6] = x;
    __syncthreads();
    float r = red[0] + red[1] + red[2] + red[3];
    __syncthreads();
    return r;
}

// ---------------- ws layout (floats) ----------------
// [0, 576)        cov
// [1024, 5120)    partial1 [16][256]
// [8192, 106496)  dataT [NV][NTOK]

// K1: transpose data (NTOK x NV) -> dataT (NV x NTOK)
__global__ __launch_bounds__(256) void k_transp(const float* __restrict__ data,
                                                float* __restrict__ dataT) {
    int idx = blockIdx.x * 256 + threadIdx.x;
    int n = idx / NV, v = idx % NV;
    dataT[v * NTOK + n] = data[idx];
}

// K2: blocks 0..575 = covavg, 576..1151 = ind MLPs
__global__ __launch_bounds__(256) void k_covind(
    const float* __restrict__ dataT,
    float* __restrict__ cov,
    const float* __restrict__ iW1, const float* __restrict__ ib1,
    const float* __restrict__ iW2, const float* __restrict__ ib2,
    float* __restrict__ out_ind) {
    __shared__ float red[256];
    const int bx = blockIdx.x;
    const int t = threadIdx.x;

    if (bx < NP) {
        int i = bx / NV, j = bx % NV;
        const float* ri = dataT + i * NTOK;
        const float* rj = dataT + j * NTOK;
        float ai0 = 0.f, ai1 = 0.f, aj0 = 0.f, aj1 = 0.f;
#pragma unroll
        for (int b = 0; b < NB; ++b) {
            ai0 += ri[b * NS + t];       ai1 += ri[b * NS + t + 256];
            aj0 += rj[b * NS + t];       aj1 += rj[b * NS + t + 256];
        }
        ai0 *= 0.125f; ai1 *= 0.125f; aj0 *= 0.125f; aj1 *= 0.125f;
        float si = blk_reduce(ai0 + ai1, red, t);
        float sj = blk_reduce(aj0 + aj1, red, t);
        float mi = si * (1.f / NS), mj = sj * (1.f / NS);
        float sd = (ai0 - mi) * (aj0 - mj) + (ai1 - mi) * (aj1 - mj);
        sd = blk_reduce(sd, red, t);
        if (t == 0) cov[bx] = sd;
    } else {
        int p = bx - NP;
        int i = p / NV, j = p % NV;
        float w0[IH], w1[IH], bb[IH], w2[IH];
        const float4* A4 = (const float4*)(iW1 + p * 2 * IH);
        const float4* B4 = (const float4*)(ib1 + p * IH);
        const float4* C4 = (const float4*)(iW2 + p * IH);
#pragma unroll
        for (int q = 0; q < 8; ++q) {
            float4 u = A4[q];
            w0[q * 4 + 0] = u.x; w0[q * 4 + 1] = u.y; w0[q * 4 + 2] = u.z; w0[q * 4 + 3] = u.w;
            float4 v4 = A4[8 + q];
            w1[q * 4 + 0] = v4.x; w1[q * 4 + 1] = v4.y; w1[q * 4 + 2] = v4.z; w1[q * 4 + 3] = v4.w;
            float4 b4 = B4[q];
            bb[q * 4 + 0] = b4.x; bb[q * 4 + 1] = b4.y; bb[q * 4 + 2] = b4.z; bb[q * 4 + 3] = b4.w;
            float4 c4 = C4[q];
            w2[q * 4 + 0] = c4.x; w2[q * 4 + 1] = c4.y; w2[q * 4 + 2] = c4.z; w2[q * 4 + 3] = c4.w;
        }
        float b2v = ib2[p];
        const float* di_p = dataT + i * NTOK;
        const float* dj_p = dataT + j * NTOK;
        float acc = 0.f;
#pragma unroll 2
        for (int k = 0; k < NTOK / 256; ++k) {
            int n = k * 256 + t;
            float di = di_p[n];
            float dj = dj_p[n];
            float s = b2v;
#pragma unroll
            for (int h = 0; h < IH; ++h) {
                float a = fmaf(di, w0[h], fmaf(dj, w1[h], bb[h]));
                a = fmaxf(a, 0.f);
                s = fmaf(a, w2[h], s);
            }
            acc += 1.f / (1.f + expf(-s));
        }
        red[t] = acc;
        __syncthreads();
        for (int st = 128; st > 0; st >>= 1) {
            if (t < st) red[t] += red[t + st];
            __syncthreads();
        }
        if (t == 0) out_ind[p] = red[0] * (1.f / NTOK);
    }
}

// K3: layer1 split-K partials. Grid 64 = 16 k-tiles x 4 o-tiles.
// Block (kt, ot): 36 ks x 64 outputs -> partial1[kt][ot*64..+64)
__global__ __launch_bounds__(256) void k_mlp1p(
    const float* __restrict__ cov,
    const float* __restrict__ sW1,
    float* __restrict__ partial1) {
    __shared__ float corrL[36];
    __shared__ float stdL[NV];
    __shared__ float P[256];
    const int bx = blockIdx.x;
    const int kt = bx >> 2, ot = bx & 3;
    const int t = threadIdx.x;
    if (t < NV) stdL[t] = sqrtf(cov[t * (NV + 1)]);
    __syncthreads();
    if (t < 36) {
        int o = kt * 36 + t;
        int i = o / NV, j = o % NV;
        float q = fabsf(cov[o] / (stdL[i] * stdL[j]));
        if (isnan(q)) q = 0.f;
        if (i == j) q = 0.f;
        corrL[t] = q;
    }
    __syncthreads();
    const int oo = t & 63, kg = t >> 6;   // 4 k-groups of 9
    float a = 0.f;
#pragma unroll
    for (int q = 0; q < 9; ++q) {
        int kl = kg * 9 + q;
        a = fmaf(corrL[kl], sW1[(kt * 36 + kl) * SH1 + ot * 64 + oo], a);
    }
    P[t] = a;
    __syncthreads();
    if (t < 64)
        partial1[kt * SH1 + ot * 64 + t] = P[t] + P[64 + t] + P[128 + t] + P[192 + t];
}

// K4: reduce partials -> h1, layer2 (parallel split-K in-block), layer3 slice.
// 9 blocks x 64 outputs.
__global__ __launch_bounds__(256) void k_mlp23(
    const float* __restrict__ partial1,
    const float* __restrict__ sb1,
    const float* __restrict__ sW2, const float* __restrict__ sb2,
    const float* __restrict__ sW3, const float* __restrict__ sb3,
    float* __restrict__ out_adj) {
    __shared__ float h1L[SH1];
    __shared__ float h2L[SH2];
    __shared__ float P[256];
    const int t = threadIdx.x, b = blockIdx.x;
    // h1[t] = relu(sb1[t] + sum_r partial1[r][t])
    {
        float s = sb1[t];
#pragma unroll
        for (int r = 0; r < 16; ++r) s += partial1[r * SH1 + t];
        h1L[t] = fmaxf(s, 0.f);
    }
    __syncthreads();
    // layer2: o = t&127, two k-halves of 128
    {
        const int o = t & 127, half = t >> 7;
        float a = 0.f;
        for (int k = half * 128; k < half * 128 + 128; ++k)
            a = fmaf(h1L[k], sW2[k * SH2 + o], a);
        P[t] = a;
        __syncthreads();
        if (t < SH2) h2L[t] = fmaxf(P[t] + P[t + 128] + sb2[t], 0.f);
        __syncthreads();
    }
    // layer3: 64 outputs for this block, 4 k-chunks of 32
    const int o = b * 64 + (t & 63), c = t >> 6;
    float pp = 0.f;
    for (int k = c * 32; k < c * 32 + 32; ++k)
        pp = fmaf(h2L[k], sW3[k * NP + o], pp);
    P[t] = pp;
    __syncthreads();
    if (t < 64) {
        int oo = b * 64 + t;
        float s = P[t] + P[64 + t] + P[128 + t] + P[192 + t] + sb3[oo];
        float sg = 1.f / (1.f + expf(-s));
        int i = oo / NV, j = oo % NV;
        out_adj[oo] = (j > i) ? sg : 0.f;
    }
}

// K5: per-variable 23->128->64->1 MLP via bf16 MFMA. 128-token chunks, grid 24x32.
__global__ __launch_bounds__(256) void k_pred(
    const float* __restrict__ data,
    const float* __restrict__ mW1, const float* __restrict__ mb1,
    const float* __restrict__ mW2, const float* __restrict__ mb2,
    const float* __restrict__ mW3, const float* __restrict__ mb3,
    const float* __restrict__ adj,
    float* __restrict__ out_pred) {
    const int v = blockIdx.x;          // 0..23
    const int chunk = blockIdx.y;      // 0..31, 128 tokens each
    const int t = threadIdx.x;

    bool hp = false;
#pragma unroll
    for (int r = 0; r < NV; ++r) hp = hp || (adj[r * NV + v] > 0.5f);
    if (!hp) {
        if (t < 128) {
            int tok = chunk * 128 + t;
            out_pred[tok * NV + v] = data[tok * NV + v];
        }
        return;
    }

    __shared__ short Xl[128 * 40];     // 10 KB
    __shared__ short WH[12288];        // 24 KB
    short* W1B = WH;                   // 32*128
    short* W2B = WH + 4096;            // 128*64
    short* Hl = WH;                    // aliased: 4 waves * 2048 shorts

    if (t < 128) {
        int tok = chunk * 128 + t;
        const float4* dr4 = (const float4*)(data + tok * NV);
        float d[24];
#pragma unroll
        for (int q = 0; q < 6; ++q) {
            float4 u = dr4[q];
            d[q * 4 + 0] = u.x; d[q * 4 + 1] = u.y; d[q * 4 + 2] = u.z; d[q * 4 + 3] = u.w;
        }
        short xr[32];
#pragma unroll
        for (int j = 0; j < 23; ++j) {
            int src = j + (j >= v ? 1 : 0);
            xr[j] = f2bf(d[src]);
        }
        xr[23] = f2bf(1.0f);
#pragma unroll
        for (int j = 24; j < 32; ++j) xr[j] = 0;
        short* xp = Xl + t * 40;
#pragma unroll
        for (int q = 0; q < 4; ++q)
            *(bf16x8*)(xp + q * 8) = *(bf16x8*)(xr + q * 8);
    }
    for (int idx = t; idx < 32 * 128; idx += 256) {
        int k = idx >> 7, h = idx & 127;
        float val = 0.f;
        if (k < 23) {
            int src = k + (k >= v ? 1 : 0);
            float pm = (adj[src * NV + v] > 0.5f) ? 1.f : 0.f;
            val = mW1[(v * 23 + k) * 128 + h] * pm;
        } else if (k == 23) {
            val = mb1[v * 128 + h];
        }
        int nt = h >> 4, nn = h & 15, kb = (k >> 3) & 3, e = k & 7;
        W1B[((nt * 4 + kb) * 16 + nn) * 8 + e] = f2bf(val);
    }
    for (int idx = t; idx < 128 * 64; idx += 256) {
        int k = idx >> 6, n = idx & 63;
        float val = mW2[(v * 128 + k) * 64 + n];
        int s = k >> 5, kb = (k >> 3) & 3, e = k & 7, nt = n >> 4, nn = n & 15;
        W2B[(((s * 4 + nt) * 4 + kb) * 16 + nn) * 8 + e] = f2bf(val);
    }
    __syncthreads();

    const int lane = t & 63;
    const int wid = t >> 6;
    const int ml = lane & 15;
    const int kb = lane >> 4;
    short* Hw = Hl + wid * 2048;

    bf16x8 w1f[8], w2f[16];
#pragma unroll
    for (int nt = 0; nt < 8; ++nt)
        w1f[nt] = *(bf16x8*)(W1B + (nt * 64 + lane) * 8);
#pragma unroll
    for (int q = 0; q < 16; ++q)
        w2f[q] = *(bf16x8*)(W2B + (q * 64 + lane) * 8);

    float b2r[4], w3r[4];
#pragma unroll
    for (int nt = 0; nt < 4; ++nt) {
        b2r[nt] = mb2[v * 64 + nt * 16 + ml];
        w3r[nt] = mW3[v * 64 + nt * 16 + ml];
    }
    float b3v = mb3[v];

    __syncthreads();   // W1B/W2B fully read before Hl (aliased) is written

#pragma unroll
    for (int mt = 0; mt < 2; ++mt) {
        int lt = wid * 32 + mt * 16 + ml;      // local token row (0..127)
        bf16x8 a1 = *(bf16x8*)(Xl + lt * 40 + kb * 8);
        f32x4 c1[8] = {};
#pragma unroll
        for (int nt = 0; nt < 8; ++nt)
            c1[nt] = __builtin_amdgcn_mfma_f32_16x16x32_bf16(a1, w1f[nt], c1[nt], 0, 0, 0);
#pragma unroll
        for (int nt = 0; nt < 8; ++nt) {
#pragma unroll
            for (int r = 0; r < 4; ++r) {
                int m = kb * 4 + r;
                int h = nt * 16 + ml;
                int bo = (m * 256 + h * 2) ^ ((m & 7) << 4);
                *(short*)((char*)Hw + bo) = f2bf(fmaxf(c1[nt][r], 0.f));
            }
        }
        f32x4 c2[4] = {};
#pragma unroll
        for (int s = 0; s < 4; ++s) {
            int c0 = s * 32 + kb * 8;
            int bo = (ml * 256 + c0 * 2) ^ ((ml & 7) << 4);
            bf16x8 a2 = *(bf16x8*)((char*)Hw + bo);
#pragma unroll
            for (int nt = 0; nt < 4; ++nt)
                c2[nt] = __builtin_amdgcn_mfma_f32_16x16x32_bf16(a2, w2f[s * 4 + nt], c2[nt], 0, 0, 0);
        }
        float sacc[4] = {0.f, 0.f, 0.f, 0.f};
#pragma unroll
        for (int nt = 0; nt < 4; ++nt) {
#pragma unroll
            for (int r = 0; r < 4; ++r)
                sacc[r] += fmaxf(c2[nt][r] + b2r[nt], 0.f) * w3r[nt];
        }
#pragma unroll
        for (int o = 1; o < 16; o <<= 1) {
#pragma unroll
            for (int r = 0; r < 4; ++r)
                sacc[r] += __shfl_xor(sacc[r], o);
        }
        if (ml == 0) {
            int tokb = chunk * 128 + wid * 32 + mt * 16 + kb * 4;
#pragma unroll
            for (int r = 0; r < 4; ++r)
                out_pred[(tokb + r) * NV + v] = sacc[r] + b3v;
        }
    }
}

extern "C" void kernel_launch(void* const* d_in, const int* in_sizes, int n_in,
                              void* d_out, int out_size, void* d_ws, size_t ws_size,
                              hipStream_t stream) {
    const float* data = (const float*)d_in[0];
    const float* sW1 = (const float*)d_in[1];
    const float* sb1 = (const float*)d_in[2];
    const float* sW2 = (const float*)d_in[3];
    const float* sb2 = (const float*)d_in[4];
    const float* sW3 = (const float*)d_in[5];
    const float* sb3 = (const float*)d_in[6];
    const float* mW1 = (const float*)d_in[7];
    const float* mb1 = (const float*)d_in[8];
    const float* mW2 = (const float*)d_in[9];
    const float* mb2 = (const float*)d_in[10];
    const float* mW3 = (const float*)d_in[11];
    const float* mb3 = (const float*)d_in[12];
    const float* iW1 = (const float*)d_in[13];
    const float* ib1 = (const float*)d_in[14];
    const float* iW2 = (const float*)d_in[15];
    const float* ib2 = (const float*)d_in[16];

    float* out = (float*)d_out;
    float* ws = (float*)d_ws;
    float* ws_cov = ws;
    float* ws_p1 = ws + 1024;
    float* ws_dataT = ws + 8192;

    k_transp<<<dim3(384), dim3(256), 0, stream>>>(data, ws_dataT);
    k_covind<<<dim3(1152), dim3(256), 0, stream>>>(ws_dataT, ws_cov,
                                                   iW1, ib1, iW2, ib2,
                                                   out + NP + NTOK * NV);
    k_mlp1p<<<dim3(64), dim3(256), 0, stream>>>(ws_cov, sW1, ws_p1);
    k_mlp23<<<dim3(9), dim3(256), 0, stream>>>(ws_p1, sb1, sW2, sb2, sW3, sb3, out);
    dim3 gp(NV, 32);
    k_pred<<<gp, dim3(256), 0, stream>>>(data, mW1, mb1, mW2, mb2, mW3, mb3,
                                         out, out + NP);
}

// Round 8
// 56.148 us; speedup vs baseline: 1.2543x; 1.2096x over previous
//
#include <hip/hip_runtime.h>
#include <math.h>

#define NV 24
#define NB 8
#define NS 512
#define NTOK 4096       // NB*NS
#define H1 128
#define H2 64
#define SH1 256
#define SH2 128
#define IH 32
#define NP 576          // NV*NV

typedef short bf16x8 __attribute__((ext_vector_type(8)));
typedef float f32x4 __attribute__((ext_vector_type(4)));

__device__ __forceinline__ short f2bf(float f) {
    union { float f; unsigned u; } x; x.f = f;
    unsigned r = x.u + 0x7fffu + ((x.u >> 16) & 1u);   // RNE
    return (short)(r >> 16);
}

__device__ __forceinline__ float blk_reduce(float x, float* red, int t) {
#pragma unroll
    for (int o = 32; o > 0; o >>= 1) x += __shfl_xor(x, o);
    if ((t & 63) == 0) red[t >> 6] = x;
    __syncthreads();
    float r = red[0] + red[1] + red[2] + red[3];
    __syncthreads();
    return r;
}

// ---------------- ws layout (floats) ----------------
// [0, 576)        cov
// [1024, 5120)    partial1 [16][256]
// [8192, 106496)  dataT [NV][NTOK]

// K1: transpose data (NTOK x NV) -> dataT (NV x NTOK)
__global__ __launch_bounds__(256) void k_transp(const float* __restrict__ data,
                                                float* __restrict__ dataT) {
    int idx = blockIdx.x * 256 + threadIdx.x;
    int n = idx / NV, v = idx % NV;
    dataT[v * NTOK + n] = data[idx];
}

// K2: blocks 0..575 = covavg, 576..1151 = ind MLPs
__global__ __launch_bounds__(256) void k_covind(
    const float* __restrict__ dataT,
    float* __restrict__ cov,
    const float* __restrict__ iW1, const float* __restrict__ ib1,
    const float* __restrict__ iW2, const float* __restrict__ ib2,
    float* __restrict__ out_ind) {
    __shared__ float red[256];
    const int bx = blockIdx.x;
    const int t = threadIdx.x;

    if (bx < NP) {
        int i = bx / NV, j = bx % NV;
        const float* ri = dataT + i * NTOK;
        const float* rj = dataT + j * NTOK;
        float ai0 = 0.f, ai1 = 0.f, aj0 = 0.f, aj1 = 0.f;
#pragma unroll
        for (int b = 0; b < NB; ++b) {
            ai0 += ri[b * NS + t];       ai1 += ri[b * NS + t + 256];
            aj0 += rj[b * NS + t];       aj1 += rj[b * NS + t + 256];
        }
        ai0 *= 0.125f; ai1 *= 0.125f; aj0 *= 0.125f; aj1 *= 0.125f;
        float si = blk_reduce(ai0 + ai1, red, t);
        float sj = blk_reduce(aj0 + aj1, red, t);
        float mi = si * (1.f / NS), mj = sj * (1.f / NS);
        float sd = (ai0 - mi) * (aj0 - mj) + (ai1 - mi) * (aj1 - mj);
        sd = blk_reduce(sd, red, t);
        if (t == 0) cov[bx] = sd;
    } else {
        int p = bx - NP;
        int i = p / NV, j = p % NV;
        float w0[IH], w1[IH], bb[IH], w2[IH];
        const float4* A4 = (const float4*)(iW1 + p * 2 * IH);
        const float4* B4 = (const float4*)(ib1 + p * IH);
        const float4* C4 = (const float4*)(iW2 + p * IH);
#pragma unroll
        for (int q = 0; q < 8; ++q) {
            float4 u = A4[q];
            w0[q * 4 + 0] = u.x; w0[q * 4 + 1] = u.y; w0[q * 4 + 2] = u.z; w0[q * 4 + 3] = u.w;
            float4 v4 = A4[8 + q];
            w1[q * 4 + 0] = v4.x; w1[q * 4 + 1] = v4.y; w1[q * 4 + 2] = v4.z; w1[q * 4 + 3] = v4.w;
            float4 b4 = B4[q];
            bb[q * 4 + 0] = b4.x; bb[q * 4 + 1] = b4.y; bb[q * 4 + 2] = b4.z; bb[q * 4 + 3] = b4.w;
            float4 c4 = C4[q];
            w2[q * 4 + 0] = c4.x; w2[q * 4 + 1] = c4.y; w2[q * 4 + 2] = c4.z; w2[q * 4 + 3] = c4.w;
        }
        float b2v = ib2[p];
        const float* di_p = dataT + i * NTOK;
        const float* dj_p = dataT + j * NTOK;
        float acc = 0.f;
#pragma unroll 2
        for (int k = 0; k < NTOK / 256; ++k) {
            int n = k * 256 + t;
            float di = di_p[n];
            float dj = dj_p[n];
            float s = b2v;
#pragma unroll
            for (int h = 0; h < IH; ++h) {
                float a = fmaf(di, w0[h], fmaf(dj, w1[h], bb[h]));
                a = fmaxf(a, 0.f);
                s = fmaf(a, w2[h], s);
            }
            acc += 1.f / (1.f + expf(-s));
        }
        red[t] = acc;
        __syncthreads();
        for (int st = 128; st > 0; st >>= 1) {
            if (t < st) red[t] += red[t + st];
            __syncthreads();
        }
        if (t == 0) out_ind[p] = red[0] * (1.f / NTOK);
    }
}

// K3: layer1 split-K partials. Grid 64 = 16 k-tiles x 4 o-tiles.
__global__ __launch_bounds__(256) void k_mlp1p(
    const float* __restrict__ cov,
    const float* __restrict__ sW1,
    float* __restrict__ partial1) {
    __shared__ float corrL[36];
    __shared__ float stdL[NV];
    __shared__ float P[256];
    const int bx = blockIdx.x;
    const int kt = bx >> 2, ot = bx & 3;
    const int t = threadIdx.x;
    if (t < NV) stdL[t] = sqrtf(cov[t * (NV + 1)]);
    __syncthreads();
    if (t < 36) {
        int o = kt * 36 + t;
        int i = o / NV, j = o % NV;
        float q = fabsf(cov[o] / (stdL[i] * stdL[j]));
        if (isnan(q)) q = 0.f;
        if (i == j) q = 0.f;
        corrL[t] = q;
    }
    __syncthreads();
    const int oo = t & 63, kg = t >> 6;   // 4 k-groups of 9
    float a = 0.f;
#pragma unroll
    for (int q = 0; q < 9; ++q) {
        int kl = kg * 9 + q;
        a = fmaf(corrL[kl], sW1[(kt * 36 + kl) * SH1 + ot * 64 + oo], a);
    }
    P[t] = a;
    __syncthreads();
    if (t < 64)
        partial1[kt * SH1 + ot * 64 + t] = P[t] + P[64 + t] + P[128 + t] + P[192 + t];
}

// K4: reduce partials -> h1; layer2 + layer3 as wide unrolled float4 streams.
// 9 blocks x 64 outputs.
__global__ __launch_bounds__(256) void k_mlp23(
    const float* __restrict__ partial1,
    const float* __restrict__ sb1,
    const float* __restrict__ sW2, const float* __restrict__ sb2,
    const float* __restrict__ sW3, const float* __restrict__ sb3,
    float* __restrict__ out_adj) {
    __shared__ float h1L[SH1];
    __shared__ float h2L[SH2];
    __shared__ float P[1024];
    const int t = threadIdx.x, b = blockIdx.x;
    // phase 1: h1[t] = relu(sb1[t] + sum_r partial1[r][t]) -- 16 independent loads
    {
        float s = sb1[t];
#pragma unroll
        for (int r = 0; r < 16; ++r) s += partial1[r * SH1 + t];
        h1L[t] = fmaxf(s, 0.f);
    }
    __syncthreads();
    // phase 2: layer2 256->128. thread=(kq=t>>5 in 0..7, oq=t&31 in 0..31).
    // 32 unrolled float4 loads per thread -> latency overlapped.
    {
        const int kq = t >> 5, oq = t & 31;
        float4 acc = {0.f, 0.f, 0.f, 0.f};
#pragma unroll
        for (int kk = 0; kk < 32; ++kk) {
            int k = kq * 32 + kk;
            float4 w = *(const float4*)(sW2 + k * SH2 + oq * 4);
            float h = h1L[k];
            acc.x = fmaf(h, w.x, acc.x); acc.y = fmaf(h, w.y, acc.y);
            acc.z = fmaf(h, w.z, acc.z); acc.w = fmaf(h, w.w, acc.w);
        }
        *(float4*)(P + kq * 128 + oq * 4) = acc;
        __syncthreads();
        if (t < SH2) {
            float s = sb2[t];
#pragma unroll
            for (int kq2 = 0; kq2 < 8; ++kq2) s += P[kq2 * 128 + t];
            h2L[t] = fmaxf(s, 0.f);
        }
        __syncthreads();
    }
    // phase 3: layer3 128->64 (this block's slice). thread=(kq=t>>4 in 0..15,
    // oq=t&15 in 0..15). 8 unrolled float4 loads per thread.
    {
        const int kq = t >> 4, oq = t & 15;
        float4 acc = {0.f, 0.f, 0.f, 0.f};
#pragma unroll
        for (int kk = 0; kk < 8; ++kk) {
            int k = kq * 8 + kk;
            float4 w = *(const float4*)(sW3 + k * NP + b * 64 + oq * 4);
            float h = h2L[k];
            acc.x = fmaf(h, w.x, acc.x); acc.y = fmaf(h, w.y, acc.y);
            acc.z = fmaf(h, w.z, acc.z); acc.w = fmaf(h, w.w, acc.w);
        }
        *(float4*)(P + kq * 64 + oq * 4) = acc;
        __syncthreads();
        if (t < 64) {
            int oo = b * 64 + t;
            float s = sb3[oo];
#pragma unroll
            for (int kq2 = 0; kq2 < 16; ++kq2) s += P[kq2 * 64 + t];
            float sg = 1.f / (1.f + expf(-s));
            int i = oo / NV, j = oo % NV;
            out_adj[oo] = (j > i) ? sg : 0.f;
        }
    }
}

// K5: per-variable 23->128->64->1 MLP via bf16 MFMA. 128-token chunks, grid 24x32.
__global__ __launch_bounds__(256) void k_pred(
    const float* __restrict__ data,
    const float* __restrict__ mW1, const float* __restrict__ mb1,
    const float* __restrict__ mW2, const float* __restrict__ mb2,
    const float* __restrict__ mW3, const float* __restrict__ mb3,
    const float* __restrict__ adj,
    float* __restrict__ out_pred) {
    const int v = blockIdx.x;          // 0..23
    const int chunk = blockIdx.y;      // 0..31, 128 tokens each
    const int t = threadIdx.x;

    bool hp = false;
#pragma unroll
    for (int r = 0; r < NV; ++r) hp = hp || (adj[r * NV + v] > 0.5f);
    if (!hp) {
        if (t < 128) {
            int tok = chunk * 128 + t;
            out_pred[tok * NV + v] = data[tok * NV + v];
        }
        return;
    }

    __shared__ short Xl[128 * 40];     // 10 KB
    __shared__ short WH[12288];        // 24 KB
    short* W1B = WH;                   // 32*128
    short* W2B = WH + 4096;            // 128*64
    short* Hl = WH;                    // aliased: 4 waves * 2048 shorts

    if (t < 128) {
        int tok = chunk * 128 + t;
        const float4* dr4 = (const float4*)(data + tok * NV);
        float d[24];
#pragma unroll
        for (int q = 0; q < 6; ++q) {
            float4 u = dr4[q];
            d[q * 4 + 0] = u.x; d[q * 4 + 1] = u.y; d[q * 4 + 2] = u.z; d[q * 4 + 3] = u.w;
        }
        short xr[32];
#pragma unroll
        for (int j = 0; j < 23; ++j) {
            int src = j + (j >= v ? 1 : 0);
            xr[j] = f2bf(d[src]);
        }
        xr[23] = f2bf(1.0f);
#pragma unroll
        for (int j = 24; j < 32; ++j) xr[j] = 0;
        short* xp = Xl + t * 40;
#pragma unroll
        for (int q = 0; q < 4; ++q)
            *(bf16x8*)(xp + q * 8) = *(bf16x8*)(xr + q * 8);
    }
    for (int idx = t; idx < 32 * 128; idx += 256) {
        int k = idx >> 7, h = idx & 127;
        float val = 0.f;
        if (k < 23) {
            int src = k + (k >= v ? 1 : 0);
            float pm = (adj[src * NV + v] > 0.5f) ? 1.f : 0.f;
            val = mW1[(v * 23 + k) * 128 + h] * pm;
        } else if (k == 23) {
            val = mb1[v * 128 + h];
        }
        int nt = h >> 4, nn = h & 15, kb = (k >> 3) & 3, e = k & 7;
        W1B[((nt * 4 + kb) * 16 + nn) * 8 + e] = f2bf(val);
    }
    for (int idx = t; idx < 128 * 64; idx += 256) {
        int k = idx >> 6, n = idx & 63;
        float val = mW2[(v * 128 + k) * 64 + n];
        int s = k >> 5, kb = (k >> 3) & 3, e = k & 7, nt = n >> 4, nn = n & 15;
        W2B[(((s * 4 + nt) * 4 + kb) * 16 + nn) * 8 + e] = f2bf(val);
    }
    __syncthreads();

    const int lane = t & 63;
    const int wid = t >> 6;
    const int ml = lane & 15;
    const int kb = lane >> 4;
    short* Hw = Hl + wid * 2048;

    bf16x8 w1f[8], w2f[16];
#pragma unroll
    for (int nt = 0; nt < 8; ++nt)
        w1f[nt] = *(bf16x8*)(W1B + (nt * 64 + lane) * 8);
#pragma unroll
    for (int q = 0; q < 16; ++q)
        w2f[q] = *(bf16x8*)(W2B + (q * 64 + lane) * 8);

    float b2r[4], w3r[4];
#pragma unroll
    for (int nt = 0; nt < 4; ++nt) {
        b2r[nt] = mb2[v * 64 + nt * 16 + ml];
        w3r[nt] = mW3[v * 64 + nt * 16 + ml];
    }
    float b3v = mb3[v];

    __syncthreads();   // W1B/W2B fully read before Hl (aliased) is written

#pragma unroll
    for (int mt = 0; mt < 2; ++mt) {
        int lt = wid * 32 + mt * 16 + ml;      // local token row (0..127)
        bf16x8 a1 = *(bf16x8*)(Xl + lt * 40 + kb * 8);
        f32x4 c1[8] = {};
#pragma unroll
        for (int nt = 0; nt < 8; ++nt)
            c1[nt] = __builtin_amdgcn_mfma_f32_16x16x32_bf16(a1, w1f[nt], c1[nt], 0, 0, 0);
#pragma unroll
        for (int nt = 0; nt < 8; ++nt) {
#pragma unroll
            for (int r = 0; r < 4; ++r) {
                int m = kb * 4 + r;
                int h = nt * 16 + ml;
                int bo = (m * 256 + h * 2) ^ ((m & 7) << 4);
                *(short*)((char*)Hw + bo) = f2bf(fmaxf(c1[nt][r], 0.f));
            }
        }
        f32x4 c2[4] = {};
#pragma unroll
        for (int s = 0; s < 4; ++s) {
            int c0 = s * 32 + kb * 8;
            int bo = (ml * 256 + c0 * 2) ^ ((ml & 7) << 4);
            bf16x8 a2 = *(bf16x8*)((char*)Hw + bo);
#pragma unroll
            for (int nt = 0; nt < 4; ++nt)
                c2[nt] = __builtin_amdgcn_mfma_f32_16x16x32_bf16(a2, w2f[s * 4 + nt], c2[nt], 0, 0, 0);
        }
        float sacc[4] = {0.f, 0.f, 0.f, 0.f};
#pragma unroll
        for (int nt = 0; nt < 4; ++nt) {
#pragma unroll
            for (int r = 0; r < 4; ++r)
                sacc[r] += fmaxf(c2[nt][r] + b2r[nt], 0.f) * w3r[nt];
        }
#pragma unroll
        for (int o = 1; o < 16; o <<= 1) {
#pragma unroll
            for (int r = 0; r < 4; ++r)
                sacc[r] += __shfl_xor(sacc[r], o);
        }
        if (ml == 0) {
            int tokb = chunk * 128 + wid * 32 + mt * 16 + kb * 4;
#pragma unroll
            for (int r = 0; r < 4; ++r)
                out_pred[(tokb + r) * NV + v] = sacc[r] + b3v;
        }
    }
}

extern "C" void kernel_launch(void* const* d_in, const int* in_sizes, int n_in,
                              void* d_out, int out_size, void* d_ws, size_t ws_size,
                              hipStream_t stream) {
    const float* data = (const float*)d_in[0];
    const float* sW1 = (const float*)d_in[1];
    const float* sb1 = (const float*)d_in[2];
    const float* sW2 = (const float*)d_in[3];
    const float* sb2 = (const float*)d_in[4];
    const float* sW3 = (const float*)d_in[5];
    const float* sb3 = (const float*)d_in[6];
    const float* mW1 = (const float*)d_in[7];
    const float* mb1 = (const float*)d_in[8];
    const float* mW2 = (const float*)d_in[9];
    const float* mb2 = (const float*)d_in[10];
    const float* mW3 = (const float*)d_in[11];
    const float* mb3 = (const float*)d_in[12];
    const float* iW1 = (const float*)d_in[13];
    const float* ib1 = (const float*)d_in[14];
    const float* iW2 = (const float*)d_in[15];
    const float* ib2 = (const float*)d_in[16];

    float* out = (float*)d_out;
    float* ws = (float*)d_ws;
    float* ws_cov = ws;
    float* ws_p1 = ws + 1024;
    float* ws_dataT = ws + 8192;

    k_transp<<<dim3(384), dim3(256), 0, stream>>>(data, ws_dataT);
    k_covind<<<dim3(1152), dim3(256), 0, stream>>>(ws_dataT, ws_cov,
                                                   iW1, ib1, iW2, ib2,
                                                   out + NP + NTOK * NV);
    k_mlp1p<<<dim3(64), dim3(256), 0, stream>>>(ws_cov, sW1, ws_p1);
    k_mlp23<<<dim3(9), dim3(256), 0, stream>>>(ws_p1, sb1, sW2, sb2, sW3, sb3, out);
    dim3 gp(NV, 32);
    k_pred<<<gp, dim3(256), 0, stream>>>(data, mW1, mb1, mW2, mb2, mW3, mb3,
                                         out, out + NP);
}